// Round 4
// baseline (904.811 us; speedup 1.0000x reference)
//
#include <hip/hip_runtime.h>

typedef unsigned short u16;
typedef float f32x4 __attribute__((ext_vector_type(4)));
typedef short s16x8 __attribute__((ext_vector_type(8)));
typedef _Float16 f16x8 __attribute__((ext_vector_type(8)));

static __device__ __forceinline__ u16 f2h(float f) {
  return __builtin_bit_cast(u16, (_Float16)f);   // RNE
}

static __device__ __forceinline__ f32x4 MFMA(s16x8 a, s16x8 b, f32x4 c) {
  return __builtin_amdgcn_mfma_f32_16x16x32_f16(
      __builtin_bit_cast(f16x8, a), __builtin_bit_cast(f16x8, b), c, 0, 0, 0);
}

// ============================================================================
// K0: convert pointwise weights fp32 -> fp16 (768*1024 elems). 768 blocks.
// ============================================================================
__global__ __launch_bounds__(256) void convw_kernel(
    const float* __restrict__ w, u16* __restrict__ wb) {
  const int i = (blockIdx.x * 256 + threadIdx.x) * 4;
  const f32x4 v = *(const f32x4*)(w + i);
  ushort4 o;
  o.x = f2h(v.x); o.y = f2h(v.y); o.z = f2h(v.z); o.w = f2h(v.w);
  *(ushort4*)(wb + i) = o;
}

// ============================================================================
// K1: depthwise 3x3 + bias on concat(x,y) [fp32 in]; out t[b][p][ic] fp16
// (ic fast) so K2's B operand is k(=ic)-contiguous. LDS transpose.
// grid (icb=16, h=64, b=16), 256 threads
// ============================================================================
__global__ __launch_bounds__(256) void dwconv_kernel(
    const float* __restrict__ x, const float* __restrict__ y,
    const float* __restrict__ dww, const float* __restrict__ dwb,
    u16* __restrict__ Tt) {
  __shared__ u16 tile[64 * 66];   // [ic_local][w], pad 66 to break bank stride
  const int icb = blockIdx.x, h = blockIdx.y, b = blockIdx.z;
  const int t = threadIdx.x;
  const int wl = t & 63, g = t >> 6;
#pragma unroll 4
  for (int i = 0; i < 16; ++i) {
    const int icl = g * 16 + i;
    const int ic = icb * 64 + icl;
    const float* src = (ic < 512) ? (x + (size_t)(b * 512 + ic) * 4096)
                                  : (y + (size_t)(b * 512 + (ic - 512)) * 4096);
    float wgt[9];
#pragma unroll
    for (int k = 0; k < 9; ++k) wgt[k] = dww[ic * 9 + k];
    float acc = dwb[ic];
#pragma unroll
    for (int dh = -1; dh <= 1; ++dh) {
      const int hh = h + dh;
      if (hh < 0 || hh > 63) continue;
#pragma unroll
      for (int dw = -1; dw <= 1; ++dw) {
        const int ww = wl + dw;
        if (ww < 0 || ww > 63) continue;
        acc += src[hh * 64 + ww] * wgt[(dh + 1) * 3 + (dw + 1)];
      }
    }
    tile[icl * 66 + wl] = f2h(acc);
  }
  __syncthreads();
  const int ic2 = t & 63, wq = t >> 6;
  const size_t outb = ((size_t)b * 4096 + h * 64) * 1024 + icb * 64 + ic2;
#pragma unroll 4
  for (int i = 0; i < 16; ++i) {
    const int wp = wq + i * 4;
    Tt[outb + (size_t)wp * 1024] = tile[ic2 * 66 + wp];
  }
}

// ============================================================================
// K2: pointwise 1x1 as NT-GEMM: FM[b][oc][p] = sum_ic W[oc][ic]*Tt[b][p][ic]+bias
// 128x128 tile, BK=64, 4 waves of 64x64, mfma 16x16x32 f16.
// grid (n=32, m=6, b=16), 256 threads
// ============================================================================
__global__ __launch_bounds__(256) void pwgemm_kernel(
    const u16* __restrict__ W, const float* __restrict__ pwb,
    const u16* __restrict__ Tt, u16* __restrict__ FM) {
  __shared__ __align__(16) u16 sA[128 * 64];
  __shared__ __align__(16) u16 sB[128 * 64];
  const int b = blockIdx.z;
  const int m0 = blockIdx.y * 128, n0 = blockIdx.x * 128;
  const int t = threadIdx.x, wv = t >> 6, lane = t & 63;
  const int mw = (wv >> 1) * 64, nw = (wv & 1) * 64;
  const int l15 = lane & 15, lq = lane >> 4;
  f32x4 acc[4][4] = {};
  const u16* Wb = W + (size_t)m0 * 1024;
  const u16* Tb = Tt + ((size_t)b * 4096 + n0) * 1024;
  for (int k0 = 0; k0 < 1024; k0 += 64) {
    s16x8 av[4], bv[4];
#pragma unroll
    for (int jj = 0; jj < 4; ++jj) {
      const int c = jj * 256 + t;           // chunk id, 1024 total
      const int row = c >> 3, col = (c & 7) * 8;
      av[jj] = *(const s16x8*)(Wb + (size_t)row * 1024 + k0 + col);
      bv[jj] = *(const s16x8*)(Tb + (size_t)row * 1024 + k0 + col);
    }
    __syncthreads();   // WAR: previous tile's reads complete
#pragma unroll
    for (int jj = 0; jj < 4; ++jj) {
      const int c = jj * 256 + t;
      const int row = c >> 3, col = (c & 7) * 8;
      *(s16x8*)&sA[row * 64 + col] = av[jj];
      *(s16x8*)&sB[row * 64 + col] = bv[jj];
    }
    __syncthreads();   // RAW: tile visible
#pragma unroll
    for (int ks = 0; ks < 2; ++ks) {
      s16x8 af[4], bfv[4];
#pragma unroll
      for (int i = 0; i < 4; ++i)
        af[i] = *(const s16x8*)&sA[(mw + i * 16 + l15) * 64 + ks * 32 + lq * 8];
#pragma unroll
      for (int j = 0; j < 4; ++j)
        bfv[j] = *(const s16x8*)&sB[(nw + j * 16 + l15) * 64 + ks * 32 + lq * 8];
#pragma unroll
      for (int i = 0; i < 4; ++i)
#pragma unroll
        for (int j = 0; j < 4; ++j)
          acc[i][j] = MFMA(af[i], bfv[j], acc[i][j]);
    }
  }
#pragma unroll
  for (int i = 0; i < 4; ++i)
#pragma unroll
    for (int r = 0; r < 4; ++r) {
      const int oc = m0 + mw + i * 16 + lq * 4 + r;
      const float bias = pwb[oc];
#pragma unroll
      for (int j = 0; j < 4; ++j) {
        const int p = n0 + nw + j * 16 + l15;
        FM[((size_t)b * 768 + oc) * 4096 + p] = f2h(acc[i][j][r] + bias);
      }
    }
}

// ============================================================================
// K3: attention per (b, h, strip of 64 Q rows). Waves split S by ROWS:
// wave wv owns Q rows [wv*16, wv*16+16) x all 256 cols -> softmax is fully
// wave-local. Output fp32. grid (strip=4, h=64, b=16), 256 threads.
// ============================================================================
__global__ __launch_bounds__(256) void attn_kernel(
    const u16* __restrict__ FM, float* __restrict__ out) {
  __shared__ __align__(16) u16 sKV[16384];  // K[256][64]; later VT[64][256]
  __shared__ __align__(16) u16 sP[16384];   // P[64][256]
  const int sb = blockIdx.x, h = blockIdx.y, b = blockIdx.z;
  const int t = threadIdx.x, wv = t >> 6, lane = t & 63;
  const int l15 = lane & 15, lq = lane >> 4;
  const u16* fmb = FM + (size_t)b * 768 * 4096;
  const int hofs = h * 64;

  // stage K[256][64] (channels 256..511): explicit loads + b128 LDS stores
#pragma unroll
  for (int it = 0; it < 8; ++it) {
    const int c = it * 256 + t;            // 2048 chunks of 8 u16
    const int d = c >> 3, w0 = (c & 7) * 8;
    const s16x8 kv = *(const s16x8*)(fmb + (size_t)(256 + d) * 4096 + hofs + w0);
    *(s16x8*)&sKV[d * 64 + w0] = kv;
  }
  // Q fragments for this wave's 16 rows (A layout: m=l15, k contiguous)
  const int qrow = sb * 64 + wv * 16 + l15;
  s16x8 qf[2];
#pragma unroll
  for (int ks = 0; ks < 2; ++ks)
    qf[ks] = *(const s16x8*)(fmb + (size_t)qrow * 4096 + hofs + ks * 32 + lq * 8);
  __syncthreads();

  // S[m][d]: m in wave's 16 rows, d = 0..255 across 16 j-blocks
  f32x4 sreg[16] = {};
#pragma unroll
  for (int ks = 0; ks < 2; ++ks)
#pragma unroll
    for (int j = 0; j < 16; ++j) {
      const s16x8 kf =
          *(const s16x8*)&sKV[(j * 16 + l15) * 64 + ks * 32 + lq * 8];
      sreg[j] = MFMA(qf[ks], kf, sreg[j]);
    }

  // wave-local softmax over d. Row m_local = lq*4 + r; cols = j*16 + l15.
  float inv[4], mx[4];
#pragma unroll
  for (int r = 0; r < 4; ++r) {
    float v = -3.4e38f;
#pragma unroll
    for (int j = 0; j < 16; ++j) v = fmaxf(v, sreg[j][r]);
#pragma unroll
    for (int mk = 1; mk < 16; mk <<= 1) v = fmaxf(v, __shfl_xor(v, mk, 64));
    mx[r] = v;
  }
#pragma unroll
  for (int r = 0; r < 4; ++r) {
    float ss = 0.f;
#pragma unroll
    for (int j = 0; j < 16; ++j) {
      const float e = __expf(fminf(sreg[j][r] - mx[r], 0.f));
      sreg[j][r] = e;
      ss += e;
    }
#pragma unroll
    for (int mk = 1; mk < 16; mk <<= 1) ss += __shfl_xor(ss, mk, 64);
    inv[r] = 1.0f / fmaxf(ss, 1e-30f);
  }
  // P -> sP[row][col] (row-major, k=col contiguous for PV A-fragments)
#pragma unroll
  for (int r = 0; r < 4; ++r) {
    const int row = wv * 16 + lq * 4 + r;
#pragma unroll
    for (int j = 0; j < 16; ++j)
      sP[row * 256 + j * 16 + l15] = f2h(sreg[j][r] * inv[r]);
  }
  __syncthreads();   // all QK reads of sKV done; P visible

  // stage V^T into sKV: VT[w][d] (channels 512..767)
#pragma unroll
  for (int it = 0; it < 8; ++it) {
    const int c = it * 256 + t;
    const int d = c >> 3, w0 = (c & 7) * 8;
    const s16x8 vv = *(const s16x8*)(fmb + (size_t)(512 + d) * 4096 + hofs + w0);
#pragma unroll
    for (int j = 0; j < 8; ++j) sKV[(w0 + j) * 256 + d] = (u16)vv[j];
  }
  __syncthreads();

  // O[m][w] = sum_d P[m][d] V[d][w]; wave's 16 rows, full K=256
  f32x4 o[4] = {};
#pragma unroll
  for (int kk = 0; kk < 8; ++kk) {
    const s16x8 pf = *(const s16x8*)&sP[(wv * 16 + l15) * 256 + kk * 32 + lq * 8];
#pragma unroll
    for (int j = 0; j < 4; ++j) {
      const s16x8 vf = *(const s16x8*)&sKV[(j * 16 + l15) * 256 + kk * 32 + lq * 8];
      o[j] = MFMA(pf, vf, o[j]);
    }
  }
  // out flat = [b][h][c][w], fp32
  const size_t ob = (((size_t)b * 64 + h) * 256 + sb * 64 + wv * 16) * 64;
#pragma unroll
  for (int j = 0; j < 4; ++j)
#pragma unroll
    for (int r = 0; r < 4; ++r)
      out[ob + (size_t)(lq * 4 + r) * 64 + j * 16 + l15] = o[j][r];
}

extern "C" void kernel_launch(void* const* d_in, const int* in_sizes, int n_in,
                              void* d_out, int out_size, void* d_ws, size_t ws_size,
                              hipStream_t stream) {
  (void)in_sizes; (void)n_in; (void)out_size; (void)ws_size;
  const float* x   = (const float*)d_in[0];
  const float* y   = (const float*)d_in[1];
  const float* dww = (const float*)d_in[2];
  const float* dwb = (const float*)d_in[3];
  const float* pww = (const float*)d_in[4];
  const float* pwb = (const float*)d_in[5];
  u16* Tt   = (u16*)d_ws;                        // [16][4096][1024] f16 = 128 MiB
  u16* FM   = Tt + (size_t)16 * 4096 * 1024;     // [16][768][4096]  f16 =  96 MiB
  u16* Wb16 = FM + (size_t)16 * 768 * 4096;      // [768][1024]      f16 = 1.5 MiB
  float* out = (float*)d_out;

  convw_kernel<<<dim3(768), 256, 0, stream>>>(pww, Wb16);
  dwconv_kernel<<<dim3(16, 64, 16), 256, 0, stream>>>(x, y, dww, dwb, Tt);
  pwgemm_kernel<<<dim3(32, 6, 16), 256, 0, stream>>>(Wb16, pwb, Tt, FM);
  attn_kernel<<<dim3(4, 64, 16), 256, 0, stream>>>(FM, out);
}